// Round 1
// 856.007 us; speedup vs baseline: 1.1041x; 1.1041x over previous
//
#include <hip/hip_runtime.h>
#include <cstdint>
#include <cstddef>

// Problem constants
#define B_   32
#define L_   1024
#define D_   512
#define M_   (B_ * L_)   // 32768 rows (b*L + l)
#define N8D  4096        // 8*D columns of U
#define SCALEF 1.4142135623730951f
#define LOG2E 1.4426950408889634f

typedef unsigned short u16;
typedef __bf16 bf16x8 __attribute__((ext_vector_type(8)));
typedef unsigned short u16x8 __attribute__((ext_vector_type(8)));
typedef unsigned short u16x4 __attribute__((ext_vector_type(4)));
typedef float f32x4 __attribute__((ext_vector_type(4)));

__device__ __forceinline__ float bf2f(u16 u) {
    union { unsigned int i; float f; } v; v.i = ((unsigned int)u) << 16; return v.f;
}
__device__ __forceinline__ u16 f2bf(float x) {
    union { float f; unsigned int i; } v; v.f = x;
    unsigned int r = (v.i + 0x7fffu + ((v.i >> 16) & 1u)) >> 16;
    return (u16)r;
}
// fast sigmoid: v_exp_f32 + v_rcp_f32 (≈1 ulp f32 — far below bf16 noise)
__device__ __forceinline__ float sigmoid_fast(float z) {
    return __builtin_amdgcn_rcpf(1.0f + __builtin_amdgcn_exp2f(-LOG2E * z));
}

// async global->LDS, 16 bytes per lane. LDS dest = wave-uniform base + lane*16.
__device__ __forceinline__ void gl2lds16(const u16* g, u16* l) {
    __builtin_amdgcn_global_load_lds(
        (const __attribute__((address_space(1))) void*)g,
        (__attribute__((address_space(3))) void*)l, 16, 0, 0);
}

#define VMW(n) asm volatile("s_waitcnt vmcnt(" #n ")" ::: "memory")

// ---------------- f32 -> bf16 convert (seqs), 8 elems/thread ----------------
__global__ __launch_bounds__(256) void f32_to_bf16(const float* __restrict__ in,
                                                   u16* __restrict__ out) {
    size_t i = ((size_t)blockIdx.x * 256 + threadIdx.x) * 8;
    f32x4 v0 = *(const f32x4*)(in + i);
    f32x4 v1 = *(const f32x4*)(in + i + 4);
    u16x8 o;
#pragma unroll
    for (int q = 0; q < 4; ++q) { o[q] = f2bf(v0[q]); o[4 + q] = f2bf(v1[q]); }
    *(u16x8*)(out + i) = o;
}

// ---------------- transpose W (K,4096) f32 -> WT bf16, rows PERMUTED ----------
// Physical WT row p holds logical W column n:  n = dir*2048 + comp*512 + d
//   -> p = dir*2048 + d*4 + comp   (GEMM output columns land scan-interleaved)
__global__ __launch_bounds__(256) void transpose_w(const float* __restrict__ in,
                                                   u16* __restrict__ out,
                                                   int R, int C) {
    __shared__ u16 tile[32][33];
    int bx = blockIdx.x * 32;
    int by = blockIdx.y * 32;
    int tx = threadIdx.x & 31;
    int ty = threadIdx.x >> 5;
#pragma unroll
    for (int i = 0; i < 32; i += 8)
        tile[ty + i][tx] = f2bf(in[(size_t)(by + ty + i) * C + bx + tx]);
    __syncthreads();
#pragma unroll
    for (int i = 0; i < 32; i += 8) {
        int n = bx + ty + i;
        int p = (n >> 11) * 2048 + ((n & 511) << 2) + ((n >> 9) & 3);
        out[(size_t)p * R + by + tx] = tile[tx][ty + i];
    }
}

// ---------------- GEMM 256x256x64 8-phase (m201-style template, plain HIP) ----
// U(M,4096) = A(M,K) * BT(4096,K)^T, all bf16.
// 8 waves (2M x 4N), per-wave out 128x64. LDS 128 KiB:
//   [buf:2][op A/B:2][kslice:2] slices of [256 rows][32 cols] bf16 (16 KiB).
// Swizzle (involution): physical byte P = L ^ ((L>>3)&0x30)  — XOR byte bits
// 4..5 with row bits 1..2. Staging keeps LDS dest LINEAR (global_load_lds
// requirement) and pre-applies the inverse swizzle to the GLOBAL source;
// ds_read applies the same XOR (lane-constant since row bits 1..2 == qm bits
// 1..2). Result: each consecutive-8-lane batch of a ds_read_b128 covers all 8
// 16B bank groups -> ~2-way (free).
// Schedule per K-tile (4 phases): P1(mh0,k0) reads A(m0,k0)+ALL B(k0) [8 rd],
// P2(mh1,k0) [4 rd], P3(mh0,k1) [8 rd], P4(mh1,k1) [4 rd]; each phase stages
// one half-tile (2 x global_load_lds, 128 rows x 32 cols); vmcnt(6) only at
// each tile's P4 (3 half-tiles in flight). Slot ledger: a region is staged
// only in a phase AFTER its last read's closing barrier; reads are covered by
// the preceding counted vmcnt + barrier. Epilogue drains 4 -> 0.
__global__ __launch_bounds__(512) void gemm256(const u16* __restrict__ A,
                                               const u16* __restrict__ BT,
                                               u16* __restrict__ U, int K) {
    extern __shared__ __align__(16) u16 lds[];   // 65536 u16 = 128 KiB
    const int t    = threadIdx.x;
    const int lane = t & 63;
    const int wave = t >> 6;
    const int wm   = wave >> 2;        // 0..1
    const int wn   = wave & 3;         // 0..3
    const int qm   = lane & 15;
    const int quad = lane >> 4;

    // T1: XCD-contiguous block swizzle (2048 blocks, 8 XCDs, bijective)
    const int nwg = gridDim.x;
    const int wg  = blockIdx.x;
    const int swz = (wg & 7) * (nwg >> 3) + (wg >> 3);
    const int bn  = (swz & 15) << 8;   // 16 N-tiles (fast: A-tile reuse in L2)
    const int bm  = (swz >> 4) << 8;   // 128 M-tiles

    // staging: thread t owns physical slice bytes [t*16, t*16+16) (+8K issue 1);
    // logical position L = P ^ ((P>>3)&0x30)  (self-inverse XOR)
    const int P0   = t * 16;
    const int L0   = P0 ^ ((P0 >> 3) & 0x30);
    const int srow = L0 >> 6;           // 0..127
    const int scol = (L0 & 63) >> 1;    // 0..31 u16, multiple of 8
    const u16* Ag = A  + (size_t)(bm + srow) * K + scol;
    const u16* Bg = BT + (size_t)(bn + srow) * K + scol;
    const size_t g128 = (size_t)128 * K;
    u16* ldst = lds + t * 8;            // linear dest: slice base + t*16 bytes

    // fragment-read lane bases (bytes within a 16 KiB slice), XOR folded in
    const int fxor  = (quad * 16) ^ ((qm & 6) << 3);
    const int aBase = (wm * 128 + qm) * 64 + fxor;
    const int bBase = (wn * 64  + qm) * 64 + fxor;
    const char* ldsc = (const char*)lds;

    f32x4 acc[8][4];
#pragma unroll
    for (int i = 0; i < 8; ++i)
#pragma unroll
        for (int j = 0; j < 4; ++j) acc[i][j] = (f32x4)(0.0f);

    bf16x8 bfr[4];   // B frags for current k-slice, live across mh phases

#define STG(op, tile, ks, buf) do {                                          \
        const u16* g_ = ((op) ? Bg : Ag) + (size_t)(tile) * 64 + (ks) * 32;  \
        u16* l_ = ldst + (buf) * 32768 + (op) * 16384 + (ks) * 8192;         \
        gl2lds16(g_, l_);                                                    \
        gl2lds16(g_ + g128, l_ + 4096);                                      \
    } while (0)

#define PHASE(buf, mh, ks, STAGE_STMT, VM_STMT) do {                         \
        const char* As_ = ldsc + ((buf) * 32768 + (ks) * 8192) * 2;          \
        const char* Bs_ = ldsc + ((buf) * 32768 + 16384 + (ks) * 8192) * 2;  \
        bf16x8 a_[4];                                                        \
        _Pragma("unroll")                                                    \
        for (int mi = 0; mi < 4; ++mi)                                       \
            a_[mi] = *(const bf16x8*)(As_ + aBase + ((mh) * 64 + mi * 16) * 64); \
        if ((mh) == 0) {                                                     \
            _Pragma("unroll")                                                \
            for (int nj = 0; nj < 4; ++nj)                                   \
                bfr[nj] = *(const bf16x8*)(Bs_ + bBase + nj * 16 * 64);      \
        }                                                                    \
        STAGE_STMT;                                                          \
        __builtin_amdgcn_s_barrier();                                        \
        asm volatile("s_waitcnt lgkmcnt(0)" ::: "memory");                   \
        __builtin_amdgcn_sched_barrier(0);                                   \
        __builtin_amdgcn_s_setprio(1);                                       \
        _Pragma("unroll")                                                    \
        for (int mi = 0; mi < 4; ++mi)                                       \
            _Pragma("unroll")                                                \
            for (int nj = 0; nj < 4; ++nj)                                   \
                acc[(mh) * 4 + mi][nj] = __builtin_amdgcn_mfma_f32_16x16x32_bf16( \
                    a_[mi], bfr[nj], acc[(mh) * 4 + mi][nj], 0, 0, 0);       \
        __builtin_amdgcn_s_setprio(0);                                       \
        VM_STMT;                                                             \
        __builtin_amdgcn_s_barrier();                                        \
    } while (0)

    const int nt = K >> 6;   // 8 (K=512) or 16 (K=1024)

    // prologue: tile0 (4 half-tiles) vmcnt(4); tile1 first 3 halves, vmcnt(6)
    STG(1, 0, 0, 0); STG(0, 0, 0, 0); STG(1, 0, 1, 0); STG(0, 0, 1, 0);
    VMW(4);
    STG(1, 1, 0, 1); STG(0, 1, 0, 1); STG(1, 1, 1, 1);
    VMW(6);
    __builtin_amdgcn_s_barrier();

    const int niter = (nt >> 1) - 1;
    for (int i = 0; i < niter; ++i) {
        const int tp1 = 2 * i + 1, tp2 = 2 * i + 2, tp3 = 2 * i + 3;
        // tile 2i   (buf0)
        PHASE(0, 0, 0, STG(0, tp1, 1, 1), );
        PHASE(0, 1, 0, STG(1, tp2, 0, 0), );
        PHASE(0, 0, 1, STG(0, tp2, 0, 0), );
        PHASE(0, 1, 1, STG(1, tp2, 1, 0), VMW(6));
        // tile 2i+1 (buf1)
        PHASE(1, 0, 0, STG(0, tp2, 1, 0), );
        PHASE(1, 1, 0, STG(1, tp3, 0, 1), );
        PHASE(1, 0, 1, STG(0, tp3, 0, 1), );
        PHASE(1, 1, 1, STG(1, tp3, 1, 1), VMW(6));
    }
    // peel: tiles nt-2 (buf0), nt-1 (buf1); drain 4 -> 0
    PHASE(0, 0, 0, STG(0, nt - 1, 1, 1), );
    PHASE(0, 1, 0, , );
    PHASE(0, 0, 1, , );
    PHASE(0, 1, 1, , VMW(4));
    PHASE(1, 0, 0, , );
    PHASE(1, 1, 0, , VMW(0));
    PHASE(1, 0, 1, , );
    PHASE(1, 1, 1, , );

#undef PHASE
#undef STG

    // epilogue: C/D layout col=lane&15, row=quad*4+reg; acc[i8] is row-frag
    // offset (i8>>2)*64 + (i8&3)*16
#pragma unroll
    for (int i8 = 0; i8 < 8; ++i8) {
        const int row0 = bm + wm * 128 + (i8 >> 2) * 64 + (i8 & 3) * 16 + quad * 4;
#pragma unroll
        for (int nj = 0; nj < 4; ++nj) {
            const int col = bn + wn * 64 + nj * 16 + qm;
#pragma unroll
            for (int r = 0; r < 4; ++r)
                U[(size_t)(row0 + r) * N8D + col] = f2bf(acc[i8][nj][r]);
        }
    }
}

// ---------------- SRU scan: one thread per (b, dir, d) ----------------
// U (interleaved): (b*L+l)*4096 + dir*2048 + d*4 + {0:xt,1:fp,2:rp,3:xp}
// H: (b*L+l)*1024 + dir*512 + d ; C: b*1024 + dir*512 + d
// PF=32 ping-pong prefetch: batch t+1 loads issue BEFORE batch t compute, so
// vmcnt waits for loads never drain the (shared-counter) h-stores.
template<bool OUT_F32>
__global__ __launch_bounds__(256) void sru_scan(const u16* __restrict__ U,
                                                const float* __restrict__ vf,
                                                const float* __restrict__ vr,
                                                const float* __restrict__ bfv,
                                                const float* __restrict__ brv,
                                                void* __restrict__ Hv,
                                                void* __restrict__ Cv) {
    constexpr int PF = 32;
    constexpr int NB = L_ / PF;  // 32 batches

    int gid = blockIdx.x * blockDim.x + threadIdx.x;  // 0..32767
    int d   = gid & (D_ - 1);
    int dir = (gid >> 9) & 1;   // uniform within a block
    int b   = gid >> 10;
    int ch  = dir * D_ + d;

    const float vf_v = vf[ch];
    const float vr_v = vr[ch];
    const float bf_v = bfv[ch];
    const float br_v = brv[ch];

    // direction-adjusted start pointers + signed element steps
    const ptrdiff_t ustep = dir ? -(ptrdiff_t)N8D : (ptrdiff_t)N8D;
    const ptrdiff_t hstep = dir ? -(ptrdiff_t)1024 : (ptrdiff_t)1024;
    const u16* p0 = U + (size_t)b * L_ * N8D + dir * 2048 + d * 4
                      + (dir ? (size_t)(L_ - 1) * N8D : 0);
    const size_t hstart = (size_t)b * L_ * 1024 + ch + (dir ? (size_t)(L_ - 1) * 1024 : 0);
    float* Hf = (float*)Hv + hstart;
    u16*   Hh = (u16*)Hv + hstart;

    float c = 0.0f;

    auto loadB = [&](u16x4 (&buf)[PF], int tb) {
        const u16* base = p0 + (ptrdiff_t)tb * PF * ustep;
#pragma unroll
        for (int i = 0; i < PF; ++i)
            buf[i] = *(const u16x4*)(base + (ptrdiff_t)i * ustep);
    };
    auto compStore = [&](u16x4 (&buf)[PF], int tb) {
        const ptrdiff_t hb = (ptrdiff_t)tb * PF * hstep;
#pragma unroll
        for (int i = 0; i < PF; ++i) {
            float xt = bf2f(buf[i][0]), fp = bf2f(buf[i][1]);
            float rp = bf2f(buf[i][2]), xp = bf2f(buf[i][3]);
            float f = sigmoid_fast(fp + vf_v * c + bf_v);
            float r = sigmoid_fast(rp + vr_v * c + br_v);
            c = f * (c - xt) + xt;                 // f*c + (1-f)*xt
            float xs = xp * SCALEF;
            float h  = r * (c - xs) + xs;          // r*c + (1-r)*xp*SCALE
            ptrdiff_t ho = hb + (ptrdiff_t)i * hstep;
            if (OUT_F32) Hf[ho] = h; else Hh[ho] = f2bf(h);
        }
    };

    u16x4 b0[PF], b1[PF];
    loadB(b0, 0);
    loadB(b1, 1);
    for (int t = 0; t < NB; t += 2) {
        compStore(b0, t);
        if (t + 2 < NB) loadB(b0, t + 2);
        compStore(b1, t + 1);
        if (t + 3 < NB) loadB(b1, t + 3);
    }

    if (OUT_F32) ((float*)Cv)[b * 1024 + ch] = c;
    else         ((u16*)Cv)[b * 1024 + ch]  = f2bf(c);
}

// ---------------- launch ----------------
extern "C" void kernel_launch(void* const* d_in, const int* in_sizes, int n_in,
                              void* d_out, int out_size, void* d_ws, size_t ws_size,
                              hipStream_t stream) {
    (void)in_sizes; (void)n_in; (void)out_size; (void)ws_size;

    const float* seqs = (const float*)d_in[0];
    const float* W0   = (const float*)d_in[1];
    const float* vf0  = (const float*)d_in[2];
    const float* vr0  = (const float*)d_in[3];
    const float* bf0  = (const float*)d_in[4];
    const float* br0  = (const float*)d_in[5];
    const float* W1   = (const float*)d_in[6];
    const float* vf1  = (const float*)d_in[7];
    const float* vr1  = (const float*)d_in[8];
    const float* bf1  = (const float*)d_in[9];
    const float* br1  = (const float*)d_in[10];
    // d_in[11] = lengths : unused by the reference

    float* out = (float*)d_out;  // [c1: 32*1024 f32][out1: 32*1024*1024 f32]
    char* ws = (char*)d_ws;

    const size_t U_BYTES  = (size_t)M_ * N8D * 2;        // 268435456
    const size_t H_BYTES  = (size_t)M_ * 1024 * 2;       // 67108864
    const size_t W0T_B    = (size_t)4096 * 512 * 2;      // 4194304
    const size_t W1T_B    = (size_t)4096 * 1024 * 2;     // 8388608

    u16* U   = (u16*)(ws);
    u16* H0  = (u16*)(ws + U_BYTES);               // also holds seqs_bf16 before scan0
    u16* S16 = H0;                                  // dead after gemm0
    u16* W0T = (u16*)(ws + U_BYTES + H_BYTES);
    u16* W1T = (u16*)(ws + U_BYTES + H_BYTES + W0T_B);
    u16* Cd  = (u16*)(ws + U_BYTES + H_BYTES + W0T_B + W1T_B);  // dummy c, layer 0

    // seqs f32 -> bf16
    f32_to_bf16<<<dim3(M_ * 512 / 8 / 256), 256, 0, stream>>>(seqs, S16);

    // W0 (512,4096) f32 -> W0T bf16 (permuted rows); W1 (1024,4096) -> W1T
    transpose_w<<<dim3(4096 / 32, 512 / 32), 256, 0, stream>>>(W0, W0T, 512, 4096);
    transpose_w<<<dim3(4096 / 32, 1024 / 32), 256, 0, stream>>>(W1, W1T, 1024, 4096);

    // Layer 0: A = seqs_bf16, K=512
    gemm256<<<dim3(2048), 512, 131072, stream>>>(S16, W0T, U, 512);
    sru_scan<false><<<dim3(M_ / 256), 256, 0, stream>>>(U, vf0, vr0, bf0, br0, (void*)H0, (void*)Cd);

    // Layer 1: A = H0 (bf16), K=1024
    gemm256<<<dim3(2048), 512, 131072, stream>>>(H0, W1T, U, 1024);
    sru_scan<true><<<dim3(M_ / 256), 256, 0, stream>>>(U, vf1, vr1, bf1, br1,
                                                       (void*)(out + B_ * 1024), (void*)out);
}

// Round 3
// 774.476 us; speedup vs baseline: 1.2204x; 1.1053x over previous
//
#include <hip/hip_runtime.h>
#include <cstdint>
#include <cstddef>

// Problem constants
#define B_   32
#define L_   1024
#define D_   512
#define M_   (B_ * L_)   // 32768 rows (b*L + l)
#define N8D  4096        // 8*D columns of U
#define SCALEF 1.4142135623730951f
#define LOG2E 1.4426950408889634f

typedef unsigned short u16;
typedef __bf16 bf16x8 __attribute__((ext_vector_type(8)));
typedef unsigned short u16x8 __attribute__((ext_vector_type(8)));
typedef unsigned short u16x4 __attribute__((ext_vector_type(4)));
typedef float f32x4 __attribute__((ext_vector_type(4)));

__device__ __forceinline__ float bf2f(u16 u) {
    union { unsigned int i; float f; } v; v.i = ((unsigned int)u) << 16; return v.f;
}
__device__ __forceinline__ u16 f2bf(float x) {
    union { float f; unsigned int i; } v; v.f = x;
    unsigned int r = (v.i + 0x7fffu + ((v.i >> 16) & 1u)) >> 16;
    return (u16)r;
}
// fast sigmoid: v_exp_f32 + v_rcp_f32 (≈1 ulp f32 — far below bf16 noise)
__device__ __forceinline__ float sigmoid_fast(float z) {
    return __builtin_amdgcn_rcpf(1.0f + __builtin_amdgcn_exp2f(-LOG2E * z));
}

// async global->LDS, 16 bytes per lane. LDS dest = wave-uniform base + lane*16.
__device__ __forceinline__ void gl2lds16(const u16* g, u16* l) {
    __builtin_amdgcn_global_load_lds(
        (const __attribute__((address_space(1))) void*)g,
        (__attribute__((address_space(3))) void*)l, 16, 0, 0);
}

#define VMW(n) asm volatile("s_waitcnt vmcnt(" #n ")" ::: "memory")

// ---------------- f32 -> bf16 convert (seqs), 8 elems/thread ----------------
__global__ __launch_bounds__(256) void f32_to_bf16(const float* __restrict__ in,
                                                   u16* __restrict__ out) {
    size_t i = ((size_t)blockIdx.x * 256 + threadIdx.x) * 8;
    f32x4 v0 = *(const f32x4*)(in + i);
    f32x4 v1 = *(const f32x4*)(in + i + 4);
    u16x8 o;
#pragma unroll
    for (int q = 0; q < 4; ++q) { o[q] = f2bf(v0[q]); o[4 + q] = f2bf(v1[q]); }
    *(u16x8*)(out + i) = o;
}

// ---------------- transpose W (K,4096) f32 -> WT bf16, rows PERMUTED ----------
// Physical WT row p holds logical W column n:  n = dir*2048 + comp*512 + d
//   -> p = dir*2048 + d*4 + comp   (GEMM output columns land scan-interleaved)
__global__ __launch_bounds__(256) void transpose_w(const float* __restrict__ in,
                                                   u16* __restrict__ out,
                                                   int R, int C) {
    __shared__ u16 tile[32][33];
    int bx = blockIdx.x * 32;
    int by = blockIdx.y * 32;
    int tx = threadIdx.x & 31;
    int ty = threadIdx.x >> 5;
#pragma unroll
    for (int i = 0; i < 32; i += 8)
        tile[ty + i][tx] = f2bf(in[(size_t)(by + ty + i) * C + bx + tx]);
    __syncthreads();
#pragma unroll
    for (int i = 0; i < 32; i += 8) {
        int n = bx + ty + i;
        int p = (n >> 11) * 2048 + ((n & 511) << 2) + ((n >> 9) & 3);
        out[(size_t)p * R + by + tx] = tile[tx][ty + i];
    }
}

// ---------------- GEMM 256x256x64 8-phase (m201-style template, plain HIP) ----
// U(M,4096) = A(M,K) * BT(4096,K)^T, all bf16.
// 8 waves (2M x 4N), per-wave out 128x64. LDS 128 KiB:
//   [buf:2][op A/B:2][kslice:2] slices of [256 rows][32 cols] bf16 (16 KiB).
// Swizzle (involution): physical byte P = L ^ ((L>>3)&0x30).
// ROTATED FRAGMENT READS: each phase's ds_reads for phase p are issued at the
// END of phase p-1 (after its MFMA cluster, before the closing barrier), so
// the LDS-read latency hides under the barrier + next phase's staging instead
// of being exposed at the per-phase lgkmcnt(0). Liveness: consecutive frag
// sets never overlap. vmcnt ledger: VMW(6) post-STG at P4/P8 (steady), peel
// VMW(4)/VMW(0). Race ledger re-verified (incl. one-phase compiler sink of
// reads past BARB, bounded by next phase's sched_barrier(0)): no phase-p read
// region overlaps phase-(p+1)'s STG target; same-region overwrites are >=2
// phases later behind a completed lgkmcnt(0) + barrier.
__global__ __launch_bounds__(512, 2) void gemm256(const u16* __restrict__ A,
                                                  const u16* __restrict__ BT,
                                                  u16* __restrict__ U, int K) {
    extern __shared__ __align__(16) u16 lds[];   // 65536 u16 = 128 KiB
    const int t    = threadIdx.x;
    const int lane = t & 63;
    const int wave = t >> 6;
    const int wm   = wave >> 2;        // 0..1
    const int wn   = wave & 3;         // 0..3
    const int qm   = lane & 15;
    const int quad = lane >> 4;

    // T1: XCD-contiguous block swizzle (2048 blocks, 8 XCDs, bijective)
    const int nwg = gridDim.x;
    const int wg  = blockIdx.x;
    const int swz = (wg & 7) * (nwg >> 3) + (wg >> 3);
    const int bn  = (swz & 15) << 8;   // 16 N-tiles (fast: A-tile reuse in L2)
    const int bm  = (swz >> 4) << 8;   // 128 M-tiles

    // staging: thread t owns physical slice bytes [t*16, t*16+16);
    // logical position L = P ^ ((P>>3)&0x30)  (self-inverse XOR)
    const int P0   = t * 16;
    const int L0   = P0 ^ ((P0 >> 3) & 0x30);
    const int srow = L0 >> 6;           // 0..127
    const int scol = (L0 & 63) >> 1;    // 0..31 u16, multiple of 8
    const u16* Ag = A  + (size_t)(bm + srow) * K + scol;
    const u16* Bg = BT + (size_t)(bn + srow) * K + scol;
    const size_t g128 = (size_t)128 * K;
    u16* ldst = lds + t * 8;            // linear dest: slice base + t*16 bytes

    // fragment-read lane bases (bytes within a 16 KiB slice), XOR folded in
    const int fxor  = (quad * 16) ^ ((qm & 6) << 3);
    const int aBase = (wm * 128 + qm) * 64 + fxor;
    const int bBase = (wn * 64  + qm) * 64 + fxor;
    const char* ldsc = (const char*)lds;

    f32x4 acc[8][4];
#pragma unroll
    for (int i = 0; i < 8; ++i)
#pragma unroll
        for (int j = 0; j < 4; ++j) acc[i][j] = (f32x4)(0.0f);

    bf16x8 aA[4], aB[4];   // A frag double-set (alternating phases)
    bf16x8 bK0[4], bK1[4]; // B frags for k-slice 0 / 1

#define STG(op, tile, ks, buf) do {                                          \
        const u16* g_ = ((op) ? Bg : Ag) + (size_t)(tile) * 64 + (ks) * 32;  \
        u16* l_ = ldst + (buf) * 32768 + (op) * 16384 + (ks) * 8192;         \
        gl2lds16(g_, l_);                                                    \
        gl2lds16(g_ + g128, l_ + 4096);                                      \
    } while (0)

#define RD_A(dst, buf, ks, mh) do {                                          \
        _Pragma("unroll")                                                    \
        for (int mi = 0; mi < 4; ++mi)                                       \
            dst[mi] = *(const bf16x8*)(ldsc + ((buf) * 65536 + (ks) * 16384) \
                          + aBase + ((mh) * 64 + mi * 16) * 64);             \
    } while (0)

#define RD_B(dst, buf, ks) do {                                              \
        _Pragma("unroll")                                                    \
        for (int nj = 0; nj < 4; ++nj)                                       \
            dst[nj] = *(const bf16x8*)(ldsc + ((buf) * 65536 + 32768 +       \
                          (ks) * 16384) + bBase + nj * 16 * 64);             \
    } while (0)

// barrier -> drain LDS reads (issued last phase) -> MFMA cluster on (AU,BU)
#define MFMA16(mh, AU, BU) do {                                              \
        __builtin_amdgcn_s_barrier();                                        \
        asm volatile("s_waitcnt lgkmcnt(0)" ::: "memory");                   \
        __builtin_amdgcn_sched_barrier(0);                                   \
        __builtin_amdgcn_s_setprio(1);                                       \
        _Pragma("unroll")                                                    \
        for (int mi = 0; mi < 4; ++mi)                                       \
            _Pragma("unroll")                                                \
            for (int nj = 0; nj < 4; ++nj)                                   \
                acc[(mh) * 4 + mi][nj] = __builtin_amdgcn_mfma_f32_16x16x32_bf16( \
                    AU[mi], BU[nj], acc[(mh) * 4 + mi][nj], 0, 0, 0);        \
        __builtin_amdgcn_s_setprio(0);                                       \
    } while (0)

#define BARB __builtin_amdgcn_s_barrier()

    const int nt = K >> 6;   // 8 (K=512) or 16 (K=1024)

    // prologue: tile0 (4 half-tiles) vmcnt(4); tile1 first 3 halves, vmcnt(6)
    STG(1, 0, 0, 0); STG(0, 0, 0, 0); STG(1, 0, 1, 0); STG(0, 0, 1, 0);
    VMW(4);
    STG(1, 1, 0, 1); STG(0, 1, 0, 1); STG(1, 1, 1, 1);
    VMW(6);
    __builtin_amdgcn_s_barrier();
    RD_A(aA, 0, 0, 0); RD_B(bK0, 0, 0);   // reads for first phase

    const int niter = (nt >> 1) - 1;
    for (int i = 0; i < niter; ++i) {
        const int tp1 = 2 * i + 1, tp2 = 2 * i + 2, tp3 = 2 * i + 3;
        // tile 2i (buf0)
        STG(0, tp1, 1, 1); MFMA16(0, aA, bK0); RD_A(aB, 0, 0, 1); BARB;
        STG(1, tp2, 0, 0); MFMA16(1, aB, bK0); RD_A(aA, 0, 1, 0); RD_B(bK1, 0, 1); BARB;
        STG(0, tp2, 0, 0); MFMA16(0, aA, bK1); RD_A(aB, 0, 1, 1); BARB;
        STG(1, tp2, 1, 0); MFMA16(1, aB, bK1); VMW(6); RD_A(aA, 1, 0, 0); RD_B(bK0, 1, 0); BARB;
        // tile 2i+1 (buf1)
        STG(0, tp2, 1, 0); MFMA16(0, aA, bK0); RD_A(aB, 1, 0, 1); BARB;
        STG(1, tp3, 0, 1); MFMA16(1, aB, bK0); RD_A(aA, 1, 1, 0); RD_B(bK1, 1, 1); BARB;
        STG(0, tp3, 0, 1); MFMA16(0, aA, bK1); RD_A(aB, 1, 1, 1); BARB;
        STG(1, tp3, 1, 1); MFMA16(1, aB, bK1); VMW(6); RD_A(aA, 0, 0, 0); RD_B(bK0, 0, 0); BARB;
    }
    // peel: tiles nt-2 (buf0), nt-1 (buf1); drain 4 -> 0
    STG(0, nt - 1, 1, 1); MFMA16(0, aA, bK0); RD_A(aB, 0, 0, 1); BARB;
    MFMA16(1, aB, bK0); RD_A(aA, 0, 1, 0); RD_B(bK1, 0, 1); BARB;
    MFMA16(0, aA, bK1); RD_A(aB, 0, 1, 1); BARB;
    MFMA16(1, aB, bK1); VMW(4); RD_A(aA, 1, 0, 0); RD_B(bK0, 1, 0); BARB;
    MFMA16(0, aA, bK0); RD_A(aB, 1, 0, 1); BARB;
    MFMA16(1, aB, bK0); VMW(0); RD_A(aA, 1, 1, 0); RD_B(bK1, 1, 1); BARB;
    MFMA16(0, aA, bK1); RD_A(aB, 1, 1, 1); BARB;
    MFMA16(1, aB, bK1); BARB;

#undef BARB
#undef MFMA16
#undef RD_B
#undef RD_A
#undef STG

    // epilogue: C/D layout col=lane&15, row=quad*4+reg; acc[i8] is row-frag
    // offset (i8>>2)*64 + (i8&3)*16
#pragma unroll
    for (int i8 = 0; i8 < 8; ++i8) {
        const int row0 = bm + wm * 128 + (i8 >> 2) * 64 + (i8 & 3) * 16 + quad * 4;
#pragma unroll
        for (int nj = 0; nj < 4; ++nj) {
            const int col = bn + wn * 64 + nj * 16 + qm;
#pragma unroll
            for (int r = 0; r < 4; ++r)
                U[(size_t)(row0 + r) * N8D + col] = f2bf(acc[i8][nj][r]);
        }
    }
}

// ---------------- SRU scan: one thread per (b, dir, d) ----------------
// U (interleaved): (b*L+l)*4096 + dir*2048 + d*4 + {0:xt,1:fp,2:rp,3:xp}
// H: (b*L+l)*1024 + dir*512 + d ; C: b*1024 + dir*512 + d
// PF=32 ping-pong prefetch: batch t+1 loads issue BEFORE batch t compute, so
// vmcnt waits for loads never drain the (shared-counter) h-stores.
// Grid 512x64 (was 128x256): 32768 threads spread over all 256 CUs
// (2 blocks/CU, 1 wave each) instead of 128 CUs — the old grid left half
// the chip idle.
template<bool OUT_F32>
__global__ __launch_bounds__(64) void sru_scan(const u16* __restrict__ U,
                                               const float* __restrict__ vf,
                                               const float* __restrict__ vr,
                                               const float* __restrict__ bfv,
                                               const float* __restrict__ brv,
                                               void* __restrict__ Hv,
                                               void* __restrict__ Cv) {
    constexpr int PF = 32;
    constexpr int NB = L_ / PF;  // 32 batches

    int gid = blockIdx.x * blockDim.x + threadIdx.x;  // 0..32767
    int d   = gid & (D_ - 1);
    int dir = (gid >> 9) & 1;   // uniform within a 64-thread block
    int b   = gid >> 10;
    int ch  = dir * D_ + d;

    const float vf_v = vf[ch];
    const float vr_v = vr[ch];
    const float bf_v = bfv[ch];
    const float br_v = brv[ch];

    // direction-adjusted start pointers + signed element steps
    const ptrdiff_t ustep = dir ? -(ptrdiff_t)N8D : (ptrdiff_t)N8D;
    const ptrdiff_t hstep = dir ? -(ptrdiff_t)1024 : (ptrdiff_t)1024;
    const u16* p0 = U + (size_t)b * L_ * N8D + dir * 2048 + d * 4
                      + (dir ? (size_t)(L_ - 1) * N8D : 0);
    const size_t hstart = (size_t)b * L_ * 1024 + ch + (dir ? (size_t)(L_ - 1) * 1024 : 0);
    float* Hf = (float*)Hv + hstart;
    u16*   Hh = (u16*)Hv + hstart;

    float c = 0.0f;

    auto loadB = [&](u16x4 (&buf)[PF], int tb) {
        const u16* base = p0 + (ptrdiff_t)tb * PF * ustep;
#pragma unroll
        for (int i = 0; i < PF; ++i)
            buf[i] = *(const u16x4*)(base + (ptrdiff_t)i * ustep);
    };
    auto compStore = [&](u16x4 (&buf)[PF], int tb) {
        const ptrdiff_t hb = (ptrdiff_t)tb * PF * hstep;
#pragma unroll
        for (int i = 0; i < PF; ++i) {
            float xt = bf2f(buf[i][0]), fp = bf2f(buf[i][1]);
            float rp = bf2f(buf[i][2]), xp = bf2f(buf[i][3]);
            float f = sigmoid_fast(fp + vf_v * c + bf_v);
            float r = sigmoid_fast(rp + vr_v * c + br_v);
            c = f * (c - xt) + xt;                 // f*c + (1-f)*xt
            float xs = xp * SCALEF;
            float h  = r * (c - xs) + xs;          // r*c + (1-r)*xp*SCALE
            ptrdiff_t ho = hb + (ptrdiff_t)i * hstep;
            if (OUT_F32) Hf[ho] = h; else Hh[ho] = f2bf(h);
        }
    };

    u16x4 b0[PF], b1[PF];
    loadB(b0, 0);
    loadB(b1, 1);
    for (int t = 0; t < NB; t += 2) {
        compStore(b0, t);
        if (t + 2 < NB) loadB(b0, t + 2);
        compStore(b1, t + 1);
        if (t + 3 < NB) loadB(b1, t + 3);
    }

    if (OUT_F32) ((float*)Cv)[b * 1024 + ch] = c;
    else         ((u16*)Cv)[b * 1024 + ch]  = f2bf(c);
}

// ---------------- launch ----------------
extern "C" void kernel_launch(void* const* d_in, const int* in_sizes, int n_in,
                              void* d_out, int out_size, void* d_ws, size_t ws_size,
                              hipStream_t stream) {
    (void)in_sizes; (void)n_in; (void)out_size; (void)ws_size;

    const float* seqs = (const float*)d_in[0];
    const float* W0   = (const float*)d_in[1];
    const float* vf0  = (const float*)d_in[2];
    const float* vr0  = (const float*)d_in[3];
    const float* bf0  = (const float*)d_in[4];
    const float* br0  = (const float*)d_in[5];
    const float* W1   = (const float*)d_in[6];
    const float* vf1  = (const float*)d_in[7];
    const float* vr1  = (const float*)d_in[8];
    const float* bf1  = (const float*)d_in[9];
    const float* br1  = (const float*)d_in[10];
    // d_in[11] = lengths : unused by the reference

    float* out = (float*)d_out;  // [c1: 32*1024 f32][out1: 32*1024*1024 f32]
    char* ws = (char*)d_ws;

    const size_t U_BYTES  = (size_t)M_ * N8D * 2;        // 268435456
    const size_t H_BYTES  = (size_t)M_ * 1024 * 2;       // 67108864
    const size_t W0T_B    = (size_t)4096 * 512 * 2;      // 4194304
    const size_t W1T_B    = (size_t)4096 * 1024 * 2;     // 8388608

    u16* U   = (u16*)(ws);
    u16* H0  = (u16*)(ws + U_BYTES);               // also holds seqs_bf16 before scan0
    u16* S16 = H0;                                  // dead after gemm0
    u16* W0T = (u16*)(ws + U_BYTES + H_BYTES);
    u16* W1T = (u16*)(ws + U_BYTES + H_BYTES + W0T_B);
    u16* Cd  = (u16*)(ws + U_BYTES + H_BYTES + W0T_B + W1T_B);  // dummy c, layer 0

    // seqs f32 -> bf16
    f32_to_bf16<<<dim3(M_ * 512 / 8 / 256), 256, 0, stream>>>(seqs, S16);

    // W0 (512,4096) f32 -> W0T bf16 (permuted rows); W1 (1024,4096) -> W1T
    transpose_w<<<dim3(4096 / 32, 512 / 32), 256, 0, stream>>>(W0, W0T, 512, 4096);
    transpose_w<<<dim3(4096 / 32, 1024 / 32), 256, 0, stream>>>(W1, W1T, 1024, 4096);

    // Layer 0: A = seqs_bf16, K=512
    gemm256<<<dim3(2048), 512, 131072, stream>>>(S16, W0T, U, 512);
    sru_scan<false><<<dim3(512), 64, 0, stream>>>(U, vf0, vr0, bf0, br0, (void*)H0, (void*)Cd);

    // Layer 1: A = H0 (bf16), K=1024
    gemm256<<<dim3(2048), 512, 131072, stream>>>(H0, W1T, U, 1024);
    sru_scan<true><<<dim3(512), 64, 0, stream>>>(U, vf1, vr1, bf1, br1,
                                                 (void*)(out + B_ * 1024), (void*)out);
}